// Round 5
// baseline (729.034 us; speedup 1.0000x reference)
//
#include <hip/hip_runtime.h>
#include <stdint.h>

// Problem constants (B, T, V, E, U)
constexpr int NB = 1024;
constexpr int NT = 80;
constexpr int NV = 50000;
constexpr int NE = 512;
constexpr int NU = 512;

typedef __attribute__((ext_vector_type(8))) __bf16 bf16x8;
typedef __attribute__((ext_vector_type(4))) float f32x4;
typedef __attribute__((ext_vector_type(4))) uint16_t u16x4;
typedef __attribute__((ext_vector_type(4))) float float4v;
typedef __attribute__((ext_vector_type(4))) uint32_t u32x4;

__device__ __forceinline__ uint16_t f2bf(float f) {
  uint32_t u = __builtin_bit_cast(uint32_t, f);
  u += 0x7FFFu + ((u >> 16) & 1u);   // round-to-nearest-even
  return (uint16_t)(u >> 16);
}
__device__ __forceinline__ float bf2f(uint16_t h) {
  uint32_t u = ((uint32_t)h) << 16;
  return __builtin_bit_cast(float, u);
}
__device__ __forceinline__ float tanh_fast(float x) {
  float e = __expf(2.0f * x);
  return 1.0f - 2.0f / (e + 1.0f);
}

// MFMA with B operand held in AGPRs (gfx950: src fields address VGPR or AGPR).
// Chains that END with this must be followed by a builtin MFMA before any
// VALU read of d (compiler inserts hazard nops only around builtins).
__device__ __forceinline__ void mfma_agprB(f32x4& d, bf16x8 a, const u32x4& b) {
  asm volatile("v_mfma_f32_16x16x32_bf16 %0, %1, %2, %0"
               : "+v"(d)
               : "v"(a), "a"(b));
}

// ---------------- prep kernels ----------------

__global__ __launch_bounds__(256) void emb_to_bf16(const float* __restrict__ in,
                                                   uint16_t* __restrict__ out) {
  int i = blockIdx.x * 256 + threadIdx.x;           // 6,400,000 float4s
  float4v v = ((const float4v*)in)[i];
  u16x4 o;
  o.x = f2bf(v.x); o.y = f2bf(v.y); o.z = f2bf(v.z); o.w = f2bf(v.w);
  ((u16x4*)out)[i] = o;
}

// Pack a [K=512][N=512] fp32 weight into MFMA-B-fragment order:
// pack[nt][ks][lane][j] = bf16( W[ks*32 + (lane>>4)*8 + j][nt*16 + (lane&15)] )
__global__ __launch_bounds__(256) void pack_w(const float* __restrict__ w,
                                              uint16_t* __restrict__ out) {
  int idx = blockIdx.x * 256 + threadIdx.x;  // 0..32767 = 32 nt * 16 ks * 64 lanes
  int lane = idx & 63;
  int ks = (idx >> 6) & 15;
  int nt = idx >> 10;
  int n  = nt * 16 + (lane & 15);
  int k0 = ks * 32 + (lane >> 4) * 8;
  uint16_t v[8];
#pragma unroll
  for (int j = 0; j < 8; j++) v[j] = f2bf(w[(size_t)(k0 + j) * NU + n]);
  u16x4* o = (u16x4*)(out + (size_t)idx * 8);
  o[0] = (u16x4){v[0], v[1], v[2], v[3]};
  o[1] = (u16x4){v[4], v[5], v[6], v[7]};
}

// ---------------- projection GEMM ----------------
// Row order t-major: flat row gm = t*NB + b; block = 64 rows of one t.
// Output tiles in MFMA C-fragment order (tile = 256 u16, elem at lane*4+r).
// Depth-3 A-gather pipeline (aP = 48 VGPR; round-4's depth-4 blew the
// 256-reg budget with acc=128 and spilled).
__global__ __launch_bounds__(256, 2) void proj_gemm(const int* __restrict__ tokens,
                                                    const uint16_t* __restrict__ embb,
                                                    const uint16_t* __restrict__ kpack,
                                                    const float* __restrict__ bias,
                                                    uint16_t* __restrict__ xkp) {
  int wave = threadIdx.x >> 6;
  int lane = threadIdx.x & 63;
  int ln15 = lane & 15;
  int quad = lane >> 4;
  int m0 = blockIdx.x * 64;      // 1280 blocks: 80 t x 16 b-groups
  int t = m0 >> 10;
  int b0 = m0 & 1023;

  int tok[4];
#pragma unroll
  for (int mt = 0; mt < 4; mt++)
    tok[mt] = tokens[(size_t)(b0 + mt * 16 + ln15) * NT + t];

  float bv[8];
#pragma unroll
  for (int nt = 0; nt < 8; nt++) bv[nt] = bias[wave * 128 + nt * 16 + ln15];

  f32x4 acc[4][8];
#pragma unroll
  for (int mt = 0; mt < 4; mt++)
#pragma unroll
    for (int nt = 0; nt < 8; nt++) acc[mt][nt] = (f32x4){0.f, 0.f, 0.f, 0.f};

  // 3-stage A pipeline
  bf16x8 aP[3][4];
#pragma unroll
  for (int s = 0; s < 3; s++)
#pragma unroll
    for (int mt = 0; mt < 4; mt++)
      aP[s][mt] = *(const bf16x8*)(embb + (size_t)tok[mt] * NE + s * 32 + quad * 8);

#pragma unroll 3
  for (int ks = 0; ks < 12; ks++) {
    int st = ks % 3;
#pragma unroll
    for (int nt = 0; nt < 8; nt++) {
      int ntg = wave * 8 + nt;
      bf16x8 bfr = *(const bf16x8*)(kpack + (((size_t)ntg * 16 + ks) * 64 + lane) * 8);
#pragma unroll
      for (int mt = 0; mt < 4; mt++)
        acc[mt][nt] = __builtin_amdgcn_mfma_f32_16x16x32_bf16(aP[st][mt], bfr, acc[mt][nt], 0, 0, 0);
    }
#pragma unroll
    for (int mt = 0; mt < 4; mt++)
      aP[st][mt] = *(const bf16x8*)(embb + (size_t)tok[mt] * NE + (ks + 3) * 32 + quad * 8);
  }
  // tail: ks12 (st0, refill ks15), ks13 (st1), ks14 (st2), ks15 (st0)
#pragma unroll
  for (int ks = 12; ks < 16; ks++) {
    int st = ks % 3;
#pragma unroll
    for (int nt = 0; nt < 8; nt++) {
      int ntg = wave * 8 + nt;
      bf16x8 bfr = *(const bf16x8*)(kpack + (((size_t)ntg * 16 + ks) * 64 + lane) * 8);
#pragma unroll
      for (int mt = 0; mt < 4; mt++)
        acc[mt][nt] = __builtin_amdgcn_mfma_f32_16x16x32_bf16(aP[st][mt], bfr, acc[mt][nt], 0, 0, 0);
    }
    if (ks == 12) {
#pragma unroll
      for (int mt = 0; mt < 4; mt++)
        aP[0][mt] = *(const bf16x8*)(embb + (size_t)tok[mt] * NE + 15 * 32 + quad * 8);
    }
  }

  // epilogue: C-fragment-order tiles, coalesced 8B/lane stores
#pragma unroll
  for (int mt = 0; mt < 4; mt++) {
    int g = (b0 >> 4) + mt;
#pragma unroll
    for (int nt = 0; nt < 8; nt++) {
      int ntg = wave * 8 + nt;
      size_t tile = ((size_t)t * 64 + g) * 32 + ntg;
      u16x4 o;
      o.x = f2bf(acc[mt][nt][0] + bv[nt]);
      o.y = f2bf(acc[mt][nt][1] + bv[nt]);
      o.z = f2bf(acc[mt][nt][2] + bv[nt]);
      o.w = f2bf(acc[mt][nt][3] + bv[nt]);
      *(u16x4*)(xkp + tile * 256 + (size_t)lane * 4) = o;
    }
  }
}

// ---------------- recurrence ----------------
// 64 blocks x 512 threads. Block g owns rows g*16..+15, all 512 cols.
// Wave w owns n-tiles w*4..+3. R tiering (per wave, 16 k-slices):
//   ks0..8  : AGPR-resident (144 AGPRs, pinned via "+a"; consumed by
//             inline-asm MFMA with AGPR B operand -> no copies, no reloads)
//   ks9     : LDS (32 KB)
//   ks10..15: streamed from L2 each step, 2-slice rolling buffer; the
//             rpack pointer is laundered through "+s" asm each iteration so
//             LICM cannot hoist the (loop-invariant) loads out of the t-loop.
// Budget: 144 AGPR + ~100 VGPR < 256 combined (2 waves/EU).
// hA double-buffered; one lgkmcnt-only s_barrier per step.
__global__ __launch_bounds__(512, 2)
void rnn_rec(const uint16_t* __restrict__ xkp,
             const uint16_t* __restrict__ rpack,
             const float* __restrict__ fcw,
             const float* __restrict__ fcb,
             float* __restrict__ out) {
  __shared__ uint16_t hA[2][64 * 16 * 8];     // 2 x 16 KB: [buf][chunk][row][8]
  __shared__ uint16_t blB[8 * 4 * 64 * 8];    // 32 KB: ks==9 frags [wave][nt][lane][8]

  int g = blockIdx.x;
  int wave = threadIdx.x >> 6;
  int lane = threadIdx.x & 63;
  int ln15 = lane & 15;
  int quad = lane >> 4;
  int nt0 = wave * 4;

  // AGPR-resident B-frags ks0..8 (144 AGPRs), loaded once and pinned
  u32x4 bfa[4][9];
#pragma unroll
  for (int nt = 0; nt < 4; nt++)
#pragma unroll
    for (int ks = 0; ks < 9; ks++) {
      bfa[nt][ks] = *(const u32x4*)(rpack + (((size_t)(nt0 + nt) * 16 + ks) * 64 + lane) * 8);
      asm volatile("" : "+a"(bfa[nt][ks]));   // force into AGPRs, opaque
    }

  // ks==9 slice into LDS
#pragma unroll
  for (int nt = 0; nt < 4; nt++)
    *(u32x4*)(blB + (((size_t)wave * 4 + nt) * 64 + lane) * 8) =
        *(const u32x4*)(rpack + (((size_t)(nt0 + nt) * 16 + 9) * 64 + lane) * 8);

  // zero h0 in buffer 0
  {
    u32x4 z = (u32x4){0u, 0u, 0u, 0u};
    ((u32x4*)hA[0])[threadIdx.x * 2] = z;
    ((u32x4*)hA[0])[threadIdx.x * 2 + 1] = z;
  }
  __syncthreads();

  for (int t = 0; t < NT; t++) {
    const uint16_t* hc = hA[t & 1];
    uint16_t* hn = hA[(t + 1) & 1];
    const uint16_t* rp = rpack;
    asm volatile("" : "+s"(rp));   // defeat LICM on the streamed-slice loads

    // xk tiles for this step (consumed after the MFMA chain)
    const uint16_t* xb = xkp + (((size_t)t * 64 + g) * 32) * 256;
    u16x4 xv[4];
#pragma unroll
    for (int nt = 0; nt < 4; nt++)
      xv[nt] = *(const u16x4*)(xb + ((size_t)(nt0 + nt)) * 256 + (size_t)lane * 4);

    // rolling stream buffers: sA <- ks10, sB <- ks11
    bf16x8 sA[4], sB[4];
#pragma unroll
    for (int nt = 0; nt < 4; nt++) {
      sA[nt] = *(const bf16x8*)(rp + (((size_t)(nt0 + nt) * 16 + 10) * 64 + lane) * 8);
      sB[nt] = *(const bf16x8*)(rp + (((size_t)(nt0 + nt) * 16 + 11) * 64 + lane) * 8);
    }

    f32x4 acc[4];
#pragma unroll
    for (int nt = 0; nt < 4; nt++) acc[nt] = (f32x4){0.f, 0.f, 0.f, 0.f};

    // ks0..8 from AGPRs (asm MFMA, B in AGPR)
#pragma unroll
    for (int ks = 0; ks < 9; ks++) {
      bf16x8 a = *(const bf16x8*)(hc + (((size_t)ks * 4 + quad) * 16 + ln15) * 8);
#pragma unroll
      for (int nt = 0; nt < 4; nt++) mfma_agprB(acc[nt], a, bfa[nt][ks]);
    }
    // ks9 from LDS (builtin)
    {
      bf16x8 a = *(const bf16x8*)(hc + (((size_t)9 * 4 + quad) * 16 + ln15) * 8);
#pragma unroll
      for (int nt = 0; nt < 4; nt++) {
        bf16x8 b = *(const bf16x8*)(blB + (((size_t)wave * 4 + nt) * 64 + lane) * 8);
        acc[nt] = __builtin_amdgcn_mfma_f32_16x16x32_bf16(a, b, acc[nt], 0, 0, 0);
      }
    }
    // ks10 (sA), refill sA <- ks12
    {
      bf16x8 a = *(const bf16x8*)(hc + (((size_t)10 * 4 + quad) * 16 + ln15) * 8);
#pragma unroll
      for (int nt = 0; nt < 4; nt++)
        acc[nt] = __builtin_amdgcn_mfma_f32_16x16x32_bf16(a, sA[nt], acc[nt], 0, 0, 0);
#pragma unroll
      for (int nt = 0; nt < 4; nt++)
        sA[nt] = *(const bf16x8*)(rp + (((size_t)(nt0 + nt) * 16 + 12) * 64 + lane) * 8);
    }
    // ks11 (sB), refill sB <- ks13
    {
      bf16x8 a = *(const bf16x8*)(hc + (((size_t)11 * 4 + quad) * 16 + ln15) * 8);
#pragma unroll
      for (int nt = 0; nt < 4; nt++)
        acc[nt] = __builtin_amdgcn_mfma_f32_16x16x32_bf16(a, sB[nt], acc[nt], 0, 0, 0);
#pragma unroll
      for (int nt = 0; nt < 4; nt++)
        sB[nt] = *(const bf16x8*)(rp + (((size_t)(nt0 + nt) * 16 + 13) * 64 + lane) * 8);
    }
    // ks12 (sA), refill sA <- ks14
    {
      bf16x8 a = *(const bf16x8*)(hc + (((size_t)12 * 4 + quad) * 16 + ln15) * 8);
#pragma unroll
      for (int nt = 0; nt < 4; nt++)
        acc[nt] = __builtin_amdgcn_mfma_f32_16x16x32_bf16(a, sA[nt], acc[nt], 0, 0, 0);
#pragma unroll
      for (int nt = 0; nt < 4; nt++)
        sA[nt] = *(const bf16x8*)(rp + (((size_t)(nt0 + nt) * 16 + 14) * 64 + lane) * 8);
    }
    // ks13 (sB), refill sB <- ks15
    {
      bf16x8 a = *(const bf16x8*)(hc + (((size_t)13 * 4 + quad) * 16 + ln15) * 8);
#pragma unroll
      for (int nt = 0; nt < 4; nt++)
        acc[nt] = __builtin_amdgcn_mfma_f32_16x16x32_bf16(a, sB[nt], acc[nt], 0, 0, 0);
#pragma unroll
      for (int nt = 0; nt < 4; nt++)
        sB[nt] = *(const bf16x8*)(rp + (((size_t)(nt0 + nt) * 16 + 15) * 64 + lane) * 8);
    }
    // ks14 (sA)
    {
      bf16x8 a = *(const bf16x8*)(hc + (((size_t)14 * 4 + quad) * 16 + ln15) * 8);
#pragma unroll
      for (int nt = 0; nt < 4; nt++)
        acc[nt] = __builtin_amdgcn_mfma_f32_16x16x32_bf16(a, sA[nt], acc[nt], 0, 0, 0);
    }
    // ks15 (sB) — last producer is a builtin: compiler inserts the
    // MFMA->VALU hazard nops before the tanh reads.
    {
      bf16x8 a = *(const bf16x8*)(hc + (((size_t)15 * 4 + quad) * 16 + ln15) * 8);
#pragma unroll
      for (int nt = 0; nt < 4; nt++)
        acc[nt] = __builtin_amdgcn_mfma_f32_16x16x32_bf16(a, sB[nt], acc[nt], 0, 0, 0);
    }

    // tanh + write h(t+1) into the other buffer
#pragma unroll
    for (int nt = 0; nt < 4; nt++) {
      int cb = (nt0 + nt) * 2 + (ln15 >> 3);   // chunk index of this col
      int j = ln15 & 7;
#pragma unroll
      for (int r = 0; r < 4; r++) {
        float h = tanh_fast(acc[nt][r] + bf2f(xv[nt][r]));
        hn[((size_t)cb * 16 + quad * 4 + r) * 8 + j] = f2bf(h);
      }
    }

    // LDS-only drain + raw barrier: vmcnt loads stay in flight
    asm volatile("s_waitcnt lgkmcnt(0)\n\ts_barrier" ::: "memory");
  }

  // final FC + sigmoid: wave w handles rows 2w, 2w+1 (h_final in buffer 0)
#pragma unroll
  for (int rr = 0; rr < 2; rr++) {
    int row = wave * 2 + rr;
    const uint16_t* hr = hA[0] + ((size_t)lane * 16 + row) * 8;  // chunk=lane
    float p = 0.f;
#pragma unroll
    for (int j = 0; j < 8; j++) p += bf2f(hr[j]) * fcw[lane * 8 + j];
#pragma unroll
    for (int off = 32; off; off >>= 1) p += __shfl_down(p, off);
    if (lane == 0) {
      float logit = p + fcb[0];
      out[g * 16 + row] = 1.0f / (1.0f + __expf(-logit));
    }
  }
}

// ---------------- launcher ----------------
extern "C" void kernel_launch(void* const* d_in, const int* in_sizes, int n_in,
                              void* d_out, int out_size, void* d_ws, size_t ws_size,
                              hipStream_t stream) {
  const int* tokens   = (const int*)d_in[0];
  const float* emb    = (const float*)d_in[1];
  const float* kernel_w = (const float*)d_in[2];
  const float* rec_w  = (const float*)d_in[3];
  const float* bias   = (const float*)d_in[4];
  const float* fcw    = (const float*)d_in[5];
  const float* fcb    = (const float*)d_in[6];
  float* out = (float*)d_out;

  // workspace: emb_bf16 51.2MB | kpack 0.5MB | rpack 0.5MB | xkp 83.9MB
  uint16_t* embb  = (uint16_t*)d_ws;
  uint16_t* kpack = embb + (size_t)NV * NE;
  uint16_t* rpack = kpack + (size_t)NE * NU;
  uint16_t* xkp   = rpack + (size_t)NU * NU;

  hipLaunchKernelGGL(emb_to_bf16, dim3(25000), dim3(256), 0, stream, emb, embb);
  hipLaunchKernelGGL(pack_w, dim3(128), dim3(256), 0, stream, kernel_w, kpack);
  hipLaunchKernelGGL(pack_w, dim3(128), dim3(256), 0, stream, rec_w, rpack);
  hipLaunchKernelGGL(proj_gemm, dim3(1280), dim3(256), 0, stream, tokens, embb, kpack, bias, xkp);
  hipLaunchKernelGGL(rnn_rec, dim3(64), dim3(512), 0, stream, xkp, rpack, fcw, fcb, out);
}

// Round 6
// 454.427 us; speedup vs baseline: 1.6043x; 1.6043x over previous
//
#include <hip/hip_runtime.h>
#include <stdint.h>

// Problem constants (B, T, V, E, U)
constexpr int NB = 1024;
constexpr int NT = 80;
constexpr int NV = 50000;
constexpr int NE = 512;
constexpr int NU = 512;

typedef __attribute__((ext_vector_type(8))) __bf16 bf16x8;
typedef __attribute__((ext_vector_type(4))) float f32x4;
typedef __attribute__((ext_vector_type(4))) uint16_t u16x4;
typedef __attribute__((ext_vector_type(4))) float float4v;
typedef __attribute__((ext_vector_type(4))) uint32_t u32x4;

__device__ __forceinline__ uint16_t f2bf(float f) {
  uint32_t u = __builtin_bit_cast(uint32_t, f);
  u += 0x7FFFu + ((u >> 16) & 1u);   // round-to-nearest-even
  return (uint16_t)(u >> 16);
}
__device__ __forceinline__ float bf2f(uint16_t h) {
  uint32_t u = ((uint32_t)h) << 16;
  return __builtin_bit_cast(float, u);
}
__device__ __forceinline__ float tanh_fast(float x) {
  float e = __expf(2.0f * x);
  return 1.0f - 2.0f / (e + 1.0f);
}

// LLC-coherent (device-scope) 16B load/store: sc0 sc1 bypass L1+L2, data
// lives at the Infinity Cache coherence point -> correct regardless of
// which XCD each block lands on. No cache-flush instructions needed.
__device__ __forceinline__ void store16_cc(uint16_t* p, u32x4 v) {
  asm volatile("global_store_dwordx4 %0, %1, off sc0 sc1" :: "v"(p), "v"(v) : "memory");
}
__device__ __forceinline__ u32x4 load16_cc(const uint16_t* p) {
  u32x4 r;
  asm volatile("global_load_dwordx4 %0, %1, off sc0 sc1" : "=v"(r) : "v"(p) : "memory");
  return r;
}

// ---------------- prep kernels ----------------

__global__ __launch_bounds__(256) void emb_to_bf16(const float* __restrict__ in,
                                                   uint16_t* __restrict__ out) {
  int i = blockIdx.x * 256 + threadIdx.x;           // 6,400,000 float4s
  float4v v = ((const float4v*)in)[i];
  u16x4 o;
  o.x = f2bf(v.x); o.y = f2bf(v.y); o.z = f2bf(v.z); o.w = f2bf(v.w);
  ((u16x4*)out)[i] = o;
}

// Pack a [K=512][N=512] fp32 weight into MFMA-B-fragment order:
// pack[nt][ks][lane][j] = bf16( W[ks*32 + (lane>>4)*8 + j][nt*16 + (lane&15)] )
__global__ __launch_bounds__(256) void pack_w(const float* __restrict__ w,
                                              uint16_t* __restrict__ out) {
  int idx = blockIdx.x * 256 + threadIdx.x;  // 0..32767 = 32 nt * 16 ks * 64 lanes
  int lane = idx & 63;
  int ks = (idx >> 6) & 15;
  int nt = idx >> 10;
  int n  = nt * 16 + (lane & 15);
  int k0 = ks * 32 + (lane >> 4) * 8;
  uint16_t v[8];
#pragma unroll
  for (int j = 0; j < 8; j++) v[j] = f2bf(w[(size_t)(k0 + j) * NU + n]);
  u16x4* o = (u16x4*)(out + (size_t)idx * 8);
  o[0] = (u16x4){v[0], v[1], v[2], v[3]};
  o[1] = (u16x4){v[4], v[5], v[6], v[7]};
}

// ---------------- projection GEMM (round-3 version, best measured) -------
__global__ __launch_bounds__(256, 2) void proj_gemm(const int* __restrict__ tokens,
                                                    const uint16_t* __restrict__ embb,
                                                    const uint16_t* __restrict__ kpack,
                                                    const float* __restrict__ bias,
                                                    uint16_t* __restrict__ xkp) {
  int wave = threadIdx.x >> 6;
  int lane = threadIdx.x & 63;
  int ln15 = lane & 15;
  int quad = lane >> 4;
  int m0 = blockIdx.x * 64;      // 1280 blocks: 80 t x 16 b-groups
  int t = m0 >> 10;
  int b0 = m0 & 1023;

  int tok[4];
#pragma unroll
  for (int mt = 0; mt < 4; mt++)
    tok[mt] = tokens[(size_t)(b0 + mt * 16 + ln15) * NT + t];

  float bv[8];
#pragma unroll
  for (int nt = 0; nt < 8; nt++) bv[nt] = bias[wave * 128 + nt * 16 + ln15];

  f32x4 acc[4][8];
#pragma unroll
  for (int mt = 0; mt < 4; mt++)
#pragma unroll
    for (int nt = 0; nt < 8; nt++) acc[mt][nt] = (f32x4){0.f, 0.f, 0.f, 0.f};

  bf16x8 aC[4], aN[4];
#pragma unroll
  for (int mt = 0; mt < 4; mt++) {
    aC[mt] = *(const bf16x8*)(embb + (size_t)tok[mt] * NE + 0 * 32 + quad * 8);
    aN[mt] = *(const bf16x8*)(embb + (size_t)tok[mt] * NE + 1 * 32 + quad * 8);
  }

#pragma unroll 1
  for (int ks = 0; ks < 16; ks++) {
    bf16x8 aF[4];
    int ksn = (ks + 2) & 15;   // wraps harmlessly for ks=14,15
#pragma unroll
    for (int mt = 0; mt < 4; mt++)
      aF[mt] = *(const bf16x8*)(embb + (size_t)tok[mt] * NE + ksn * 32 + quad * 8);
#pragma unroll
    for (int nt = 0; nt < 8; nt++) {
      int ntg = wave * 8 + nt;
      bf16x8 bfr = *(const bf16x8*)(kpack + (((size_t)ntg * 16 + ks) * 64 + lane) * 8);
#pragma unroll
      for (int mt = 0; mt < 4; mt++)
        acc[mt][nt] = __builtin_amdgcn_mfma_f32_16x16x32_bf16(aC[mt], bfr, acc[mt][nt], 0, 0, 0);
    }
#pragma unroll
    for (int mt = 0; mt < 4; mt++) { aC[mt] = aN[mt]; aN[mt] = aF[mt]; }
  }

  // epilogue: C-fragment-order tiles, coalesced 8B/lane stores
#pragma unroll
  for (int mt = 0; mt < 4; mt++) {
    int g = (b0 >> 4) + mt;
#pragma unroll
    for (int nt = 0; nt < 8; nt++) {
      int ntg = wave * 8 + nt;
      size_t tile = ((size_t)t * 64 + g) * 32 + ntg;
      u16x4 o;
      o.x = f2bf(acc[mt][nt][0] + bv[nt]);
      o.y = f2bf(acc[mt][nt][1] + bv[nt]);
      o.z = f2bf(acc[mt][nt][2] + bv[nt]);
      o.w = f2bf(acc[mt][nt][3] + bv[nt]);
      *(u16x4*)(xkp + tile * 256 + (size_t)lane * 4) = o;
    }
  }
}

// ---------------- recurrence: 4-CU split, R register-resident ------------
// 256 blocks x 256 threads (1 per CU). Block (g = bid&63, s = bid>>6):
// rows g*16..+15, cols s*128..+127. Wave w owns n-tiles s*8+2w, +1.
// B-frags: 2 nt x 16 ks x 16B = 128 VGPRs, held at 1 wave/SIMD (512-reg
// budget -> no remat). h-exchange via parity-2 LLC buffer (sc0 sc1 ops) +
// per-(g,s) monotonic flags. LDS: one 16 KB h-tile in A-frag layout
// [ks][row(16)][quad(4)][j(8)]; global chunk layout == LDS region layout,
// so copy-out/staging are linear 16B/lane copies.
__global__ __launch_bounds__(256, 1)
void rnn_rec(const uint16_t* __restrict__ xkp,
             const uint16_t* __restrict__ rpack,
             const float* __restrict__ fcw,
             const float* __restrict__ fcb,
             uint16_t* __restrict__ hx,    // [2][64][4][2048] u16 (4KB chunks)
             int* __restrict__ flags,      // [64][4] stride-16 ints (64B apart)
             float* __restrict__ out) {
  __shared__ uint16_t hS[16 * 16 * 4 * 8];   // 16 KB

  const int bid = blockIdx.x;
  const int g = bid & 63, s = bid >> 6;
  const int wave = threadIdx.x >> 6, lane = threadIdx.x & 63;
  const int ln15 = lane & 15, quad = lane >> 4;
  const int ntg0 = s * 8 + wave * 2;

  // B-frags, loaded once (128 VGPRs; no occupancy pressure at 1 wave/EU)
  bf16x8 bf0[16], bf1[16];
#pragma unroll
  for (int ks = 0; ks < 16; ks++) {
    bf0[ks] = *(const bf16x8*)(rpack + (((size_t)(ntg0 + 0) * 16 + ks) * 64 + lane) * 8);
    bf1[ks] = *(const bf16x8*)(rpack + (((size_t)(ntg0 + 1) * 16 + ks) * 64 + lane) * 8);
  }

  // h(0) = 0: zero the whole hS tile
  {
    u32x4 z = (u32x4){0u, 0u, 0u, 0u};
#pragma unroll
    for (int i = 0; i < 4; i++) ((u32x4*)hS)[i * 256 + threadIdx.x] = z;
  }
  __syncthreads();

  int* myflag = flags + (g * 4 + s) * 16;

  for (int t = 0; t < NT; t++) {
    // xk tiles (plain cached loads; written by proj_gemm earlier)
    const uint16_t* xb = xkp + (((size_t)t * 64 + g) * 32) * 256;
    u16x4 xv0 = *(const u16x4*)(xb + (size_t)(ntg0 + 0) * 256 + (size_t)lane * 4);
    u16x4 xv1 = *(const u16x4*)(xb + (size_t)(ntg0 + 1) * 256 + (size_t)lane * 4);

    // compute: A from LDS, B from registers
    f32x4 acc0 = (f32x4){0.f, 0.f, 0.f, 0.f};
    f32x4 acc1 = (f32x4){0.f, 0.f, 0.f, 0.f};
#pragma unroll
    for (int ks = 0; ks < 16; ks++) {
      bf16x8 a = *(const bf16x8*)(hS + (size_t)ks * 512 + ln15 * 32 + quad * 8);
      acc0 = __builtin_amdgcn_mfma_f32_16x16x32_bf16(a, bf0[ks], acc0, 0, 0, 0);
      acc1 = __builtin_amdgcn_mfma_f32_16x16x32_bf16(a, bf1[ks], acc1, 0, 0, 0);
    }

    // tanh
    uint16_t hv0[4], hv1[4];
#pragma unroll
    for (int r = 0; r < 4; r++) {
      hv0[r] = f2bf(tanh_fast(acc0[r] + bf2f(xv0[r])));
      hv1[r] = f2bf(tanh_fast(acc1[r] + bf2f(xv1[r])));
    }

    __syncthreads();   // B2: all hS reads of step t done

    // repack own chunk into hS region ks = s*4..+3 (this IS the staging of
    // our own 128 cols for step t+1)
#pragma unroll
    for (int i = 0; i < 2; i++) {
      int col128 = (wave * 2 + i) * 16 + ln15;
      int kloc = col128 >> 5, qw = (col128 >> 3) & 3, j = col128 & 7;
      const uint16_t* hv = (i == 0) ? hv0 : hv1;
#pragma unroll
      for (int r = 0; r < 4; r++) {
        int row = quad * 4 + r;
        hS[(size_t)(s * 4 + kloc) * 512 + row * 32 + qw * 8 + j] = hv[r];
      }
    }
    __syncthreads();   // B3: own region repacked

    // copy-out own 4KB chunk to hx[(t+1)&1][g][s] (LLC-coherent stores)
    {
      u32x4 d = *(const u32x4*)(hS + (size_t)s * 2048 + (size_t)threadIdx.x * 8);
      uint16_t* dst = hx + ((size_t)((t + 1) & 1) * 256 + g * 4 + s) * 2048 +
                      (size_t)threadIdx.x * 8;
      store16_cc(dst, d);
      asm volatile("s_waitcnt vmcnt(0)" ::: "memory");
    }
    __syncthreads();   // B4: all chunk stores at LLC

    if (threadIdx.x == 0)
      __hip_atomic_store(myflag, t + 1, __ATOMIC_RELAXED, __HIP_MEMORY_SCOPE_AGENT);

    // staging: wave w in {1,2,3} fetches chunk of slice sp = (s+w)&3
    if (wave > 0) {
      int sp = (s + wave) & 3;
      int* fp = flags + (g * 4 + sp) * 16;
      int spin = 0;
      while (__hip_atomic_load(fp, __ATOMIC_RELAXED, __HIP_MEMORY_SCOPE_AGENT) < t + 1 &&
             spin < (1 << 16))
        spin++;
      asm volatile("" ::: "memory");
      const uint16_t* src = hx + ((size_t)((t + 1) & 1) * 256 + g * 4 + sp) * 2048;
      u32x4 v[4];
#pragma unroll
      for (int i = 0; i < 4; i++) v[i] = load16_cc(src + (size_t)(i * 64 + lane) * 8);
      asm volatile("s_waitcnt vmcnt(0)" ::: "memory");
#pragma unroll
      for (int i = 0; i < 4; i++)
        *(u32x4*)(hS + (size_t)sp * 2048 + (size_t)(i * 64 + lane) * 8) = v[i];
    }
    __syncthreads();   // B5: h(t+1) fully staged
  }

  // final FC + sigmoid: hS holds h(80); s==0 blocks write the 16 outputs
  if (s == 0) {
#pragma unroll
    for (int rr = 0; rr < 4; rr++) {
      int row = wave * 4 + rr;
      // cols lane*8..+7: ks = lane>>2, qw = lane&3 -> contiguous 16B
      const uint16_t* hr = hS + (size_t)(lane >> 2) * 512 + row * 32 + (lane & 3) * 8;
      float p = 0.f;
#pragma unroll
      for (int j = 0; j < 8; j++) p += bf2f(hr[j]) * fcw[lane * 8 + j];
#pragma unroll
      for (int off = 32; off; off >>= 1) p += __shfl_down(p, off);
      if (lane == 0) {
        float logit = p + fcb[0];
        out[g * 16 + row] = 1.0f / (1.0f + __expf(-logit));
      }
    }
  }
}

// ---------------- launcher ----------------
extern "C" void kernel_launch(void* const* d_in, const int* in_sizes, int n_in,
                              void* d_out, int out_size, void* d_ws, size_t ws_size,
                              hipStream_t stream) {
  const int* tokens   = (const int*)d_in[0];
  const float* emb    = (const float*)d_in[1];
  const float* kernel_w = (const float*)d_in[2];
  const float* rec_w  = (const float*)d_in[3];
  const float* bias   = (const float*)d_in[4];
  const float* fcw    = (const float*)d_in[5];
  const float* fcb    = (const float*)d_in[6];
  float* out = (float*)d_out;

  // workspace: emb_bf16 51.2MB | kpack 0.5MB | rpack 0.5MB | xkp 83.9MB |
  //            hx 2MB | flags 16KB   (~138.1 MB)
  uint16_t* embb  = (uint16_t*)d_ws;
  uint16_t* kpack = embb + (size_t)NV * NE;
  uint16_t* rpack = kpack + (size_t)NE * NU;
  uint16_t* xkp   = rpack + (size_t)NU * NU;
  uint16_t* hx    = xkp + (size_t)NT * NB * NU;            // 1,048,576 u16
  int* flags      = (int*)(hx + (size_t)2 * 256 * 2048);
  // flags poisoned 0xAA -> 0xAAAAAAAA < 1 as signed int: valid initial state.

  hipLaunchKernelGGL(emb_to_bf16, dim3(25000), dim3(256), 0, stream, emb, embb);
  hipLaunchKernelGGL(pack_w, dim3(128), dim3(256), 0, stream, kernel_w, kpack);
  hipLaunchKernelGGL(pack_w, dim3(128), dim3(256), 0, stream, rec_w, rpack);
  hipLaunchKernelGGL(proj_gemm, dim3(1280), dim3(256), 0, stream, tokens, embb, kpack, bias, xkp);
  hipLaunchKernelGGL(rnn_rec, dim3(256), dim3(256), 0, stream, xkp, rpack, fcw, fcb, hx, flags, out);
}